// Round 3
// baseline (1106.897 us; speedup 1.0000x reference)
//
#include <hip/hip_runtime.h>
#include <hip/hip_cooperative_groups.h>

namespace cg = cooperative_groups;

#define DIMN 2048
#define HDIM 8192

// ws layout (float offsets)
#define WS_Q    2048     // 2048  q vector
#define WS_ATTN 4096     // 2048  attention output accumulator (fp32, atomics)
#define WS_X1   6144     // 2048  x + attn@o_w.T + o_b
#define WS_H    10240    // 8192  gelu(fc1)
#define WS_SC   18432    // 8192  attention scores

__device__ __forceinline__ float dot4(float4 w, float4 a) {
    return w.x * a.x + w.y * a.y + w.z * a.z + w.w * a.w;
}

__device__ __forceinline__ float waveSum(float v) {
#pragma unroll
    for (int off = 32; off > 0; off >>= 1) v += __shfl_down(v, off, 64);
    return v;  // lane 0 holds the sum
}

// block-level sum over 256 threads (4 waves); red is 4-float LDS scratch
__device__ __forceinline__ float blockSum256(float v, float* red) {
    v = waveSum(v);
    int wave = threadIdx.x >> 6, lane = threadIdx.x & 63;
    if (lane == 0) red[wave] = v;
    __syncthreads();
    float r = red[0] + red[1] + red[2] + red[3];
    __syncthreads();
    return r;
}

__device__ __forceinline__ float blockMax256(float v, float* red) {
#pragma unroll
    for (int off = 32; off > 0; off >>= 1) v = fmaxf(v, __shfl_down(v, off, 64));
    int wave = threadIdx.x >> 6, lane = threadIdx.x & 63;
    if (lane == 0) red[wave] = v;
    __syncthreads();
    float r = fmaxf(fmaxf(red[0], red[1]), fmaxf(red[2], red[3]));
    __syncthreads();
    return r;
}

// Grid-wide sync with EXPLICIT agent-scope fences. On MI355X the 8 per-XCD
// L2s are non-coherent; __threadfence() emits the agent-scope writeback +
// invalidate (buffer_wbl2/buffer_inv sc1). Bracketing the library barrier
// with our own fences makes plain-load/store visibility correct even if the
// ockl grid-sync's internal fences are weaker than agent scope:
//   release fence -> coherent atomic rendezvous -> acquire fence.
__device__ __forceinline__ void gsync(cg::grid_group& g) {
    __threadfence();   // release: write back our dirty lines past local L2
    g.sync();          // rendezvous (atomics are HW-coherent device-wide)
    __threadfence();   // acquire: invalidate stale local cache lines
}

// One cooperative kernel: all 6 stages with fenced grid-wide syncs between.
// 512 blocks x 256 threads; __launch_bounds__(256,2) guarantees 2 blocks/CU
// co-residency (512 = 256 CUs x 2). Grid has 2048 waves (gw in [0,2048)).
__global__ __launch_bounds__(256, 2) void k_fused(
        const float* __restrict__ x,
        float* __restrict__ cacheK, float* __restrict__ cacheV,
        const float* __restrict__ anw,
        const float* __restrict__ qw, const float* __restrict__ qb,
        const float* __restrict__ kw, const float* __restrict__ kb,
        const float* __restrict__ vw, const float* __restrict__ vb,
        const float* __restrict__ ow, const float* __restrict__ ob,
        const float* __restrict__ mnw,
        const float* __restrict__ w1, const float* __restrict__ b1,
        const float* __restrict__ w2, const float* __restrict__ b2,
        const int* __restrict__ posp,
        float* __restrict__ ws, float* __restrict__ out) {
    cg::grid_group grid = cg::this_grid();
    __shared__ float xn[DIMN];
    __shared__ float red[4];
    const int tid = threadIdx.x, wave = tid >> 6, lane = tid & 63;
    const int bid = blockIdx.x;
    const int gw = bid * 4 + wave;  // global wave id, 0..2047
    const int pos = posp[0];
    const int L = pos + 1;

    // ---- stage A: rmsnorm(x) -> LDS (block-redundant); q/k/v GEMV rows ----
    {
        float4 a = reinterpret_cast<const float4*>(x)[tid * 2];
        float4 b = reinterpret_cast<const float4*>(x)[tid * 2 + 1];
        float ss = blockSum256(dot4(a, a) + dot4(b, b), red);
        float scale = rsqrtf(ss / (float)DIMN + 1e-6f);
        float4 wa = reinterpret_cast<const float4*>(anw)[tid * 2];
        float4 wb = reinterpret_cast<const float4*>(anw)[tid * 2 + 1];
        reinterpret_cast<float4*>(xn)[tid * 2] =
            make_float4(a.x * scale * wa.x, a.y * scale * wa.y,
                        a.z * scale * wa.z, a.w * scale * wa.w);
        reinterpret_cast<float4*>(xn)[tid * 2 + 1] =
            make_float4(b.x * scale * wb.x, b.y * scale * wb.y,
                        b.z * scale * wb.z, b.w * scale * wb.w);
        if (bid == 0) {  // zero the fp32 attention accumulator (used after 2 syncs)
            float4 z = make_float4(0.f, 0.f, 0.f, 0.f);
            reinterpret_cast<float4*>(ws + WS_ATTN)[tid * 2] = z;
            reinterpret_cast<float4*>(ws + WS_ATTN)[tid * 2 + 1] = z;
        }
        __syncthreads();
        const float4* xv = reinterpret_cast<const float4*>(xn);
        for (int row = gw; row < 3 * DIMN; row += 2048) {  // 3 rows/wave
            int mat = row >> 11, r = row & (DIMN - 1);
            const float* W = (mat == 0) ? qw : (mat == 1) ? kw : vw;
            const float* B = (mat == 0) ? qb : (mat == 1) ? kb : vb;
            const float4* wrow = reinterpret_cast<const float4*>(W + (size_t)r * DIMN);
            float acc = 0.f;
#pragma unroll
            for (int i = 0; i < 8; ++i) {
                int ch = lane + i * 64;
                acc += dot4(wrow[ch], xv[ch]);
            }
            acc = waveSum(acc);
            if (lane == 0) {
                float y = acc + B[r];
                if (mat == 0) {
                    ws[WS_Q + r] = y;
                } else {
                    float* dst = (mat == 1) ? cacheK : cacheV;
                    dst[(size_t)pos * DIMN + r] = y;
                }
            }
        }
    }
    gsync(grid);

    // ---- stage B: scores[t] = dot(K[t], q) / sqrt(d) ----
    {
        const float4* qv = reinterpret_cast<const float4*>(ws + WS_Q);
        for (int t = gw; t < L; t += 2048) {
            const float4* krow = reinterpret_cast<const float4*>(cacheK + (size_t)t * DIMN);
            float acc = 0.f;
#pragma unroll
            for (int i = 0; i < 8; ++i) {
                int ch = lane + i * 64;
                acc += dot4(krow[ch], qv[ch]);
            }
            acc = waveSum(acc);
            if (lane == 0) ws[WS_SC + t] = acc * 0.022097086912079608f;  // 1/sqrt(2048)
        }
    }
    gsync(grid);

    // ---- stage C: block-redundant softmax stats; attn += p_t * V[t,:] ----
    {
        float m = -1e30f;
        for (int i = tid; i < L; i += 256) m = fmaxf(m, ws[WS_SC + i]);
        m = blockMax256(m, red);
        float s = 0.f;
        for (int i = tid; i < L; i += 256) s += expf(ws[WS_SC + i] - m);
        s = blockSum256(s, red);
        float inv = 1.0f / s;
        int chunk = bid >> 2;                 // 128 t-chunks
        int t0 = (int)((long long)chunk * L / 128);
        int t1 = (int)((long long)(chunk + 1) * L / 128);
        int c2 = (bid & 3) * 256 + tid;       // float-pair column, 0..1023
        const float2* Vp = reinterpret_cast<const float2*>(cacheV);
        float a0 = 0.f, a1 = 0.f;
        for (int t = t0; t < t1; ++t) {
            float p = expf(ws[WS_SC + t] - m) * inv;
            float2 v = Vp[(size_t)t * (DIMN / 2) + c2];
            a0 += p * v.x;
            a1 += p * v.y;
        }
        atomicAdd(&ws[WS_ATTN + 2 * c2], a0);
        atomicAdd(&ws[WS_ATTN + 2 * c2 + 1], a1);
    }
    gsync(grid);

    // ---- stage D: x1 = x + attn @ o_w.T + o_b ----
    {
        int r = gw;  // exactly one row per wave (2048 waves, 2048 rows)
        const float4* wrow = reinterpret_cast<const float4*>(ow + (size_t)r * DIMN);
        const float4* av = reinterpret_cast<const float4*>(ws + WS_ATTN);
        float acc = 0.f;
#pragma unroll
        for (int i = 0; i < 8; ++i) {
            int ch = lane + i * 64;
            acc += dot4(wrow[ch], av[ch]);
        }
        acc = waveSum(acc);
        if (lane == 0) ws[WS_X1 + r] = x[r] + acc + ob[r];
    }
    gsync(grid);

    // ---- stage E: rmsnorm(x1) -> LDS (block-redundant); h = gelu(fc1) ----
    {
        float4 a = reinterpret_cast<const float4*>(ws + WS_X1)[tid * 2];
        float4 b = reinterpret_cast<const float4*>(ws + WS_X1)[tid * 2 + 1];
        float ss = blockSum256(dot4(a, a) + dot4(b, b), red);
        float scale = rsqrtf(ss / (float)DIMN + 1e-6f);
        float4 wa = reinterpret_cast<const float4*>(mnw)[tid * 2];
        float4 wb = reinterpret_cast<const float4*>(mnw)[tid * 2 + 1];
        reinterpret_cast<float4*>(xn)[tid * 2] =
            make_float4(a.x * scale * wa.x, a.y * scale * wa.y,
                        a.z * scale * wa.z, a.w * scale * wa.w);
        reinterpret_cast<float4*>(xn)[tid * 2 + 1] =
            make_float4(b.x * scale * wb.x, b.y * scale * wb.y,
                        b.z * scale * wb.z, b.w * scale * wb.w);
        __syncthreads();
        const float4* hv = reinterpret_cast<const float4*>(xn);
        for (int row = gw; row < HDIM; row += 2048) {  // 4 rows/wave
            const float4* wrow = reinterpret_cast<const float4*>(w1 + (size_t)row * DIMN);
            float acc = 0.f;
#pragma unroll
            for (int i = 0; i < 8; ++i) {
                int ch = lane + i * 64;
                acc += dot4(wrow[ch], hv[ch]);
            }
            acc = waveSum(acc);
            if (lane == 0) {
                float t = acc + b1[row];
                ws[WS_H + row] = 0.5f * t * (1.0f + erff(t * 0.70710678118654752f));
            }
        }
    }
    gsync(grid);

    // ---- stage F: out = x1 + h @ fc2_w.T + fc2_b — one wave per FULL row ----
    {
        const float4* hv = reinterpret_cast<const float4*>(ws + WS_H);
        int r = gw;  // 0..2047
        const float4* wrow = reinterpret_cast<const float4*>(w2 + (size_t)r * HDIM);
        float acc = 0.f;
#pragma unroll
        for (int i = 0; i < 32; ++i) {
            int ch = lane + i * 64;
            acc += dot4(wrow[ch], hv[ch]);
        }
        acc = waveSum(acc);
        if (lane == 0) out[r] = ws[WS_X1 + r] + acc + b2[r];
    }
}

// ---------------- fallback: known-good 6-kernel pipeline (round 0) ----------
__global__ __launch_bounds__(256) void k_qkv(
        const float* __restrict__ x, const float* __restrict__ anw,
        float* __restrict__ ws,
        const float* __restrict__ qw, const float* __restrict__ qb,
        const float* __restrict__ kw, const float* __restrict__ kb,
        const float* __restrict__ vw, const float* __restrict__ vb,
        float* __restrict__ cacheK, float* __restrict__ cacheV,
        const int* __restrict__ posp) {
    __shared__ float xn[DIMN];
    __shared__ float red[4];
    int tid = threadIdx.x, wave = tid >> 6, lane = tid & 63;
    int row = blockIdx.x * 4 + wave;
    int mat = row >> 11, r = row & (DIMN - 1);
    const float* W = (mat == 0) ? qw : (mat == 1) ? kw : vw;
    const float* B = (mat == 0) ? qb : (mat == 1) ? kb : vb;
    const float4* wrow = reinterpret_cast<const float4*>(W + (size_t)r * DIMN);
    float4 wr[8];
#pragma unroll
    for (int i = 0; i < 8; ++i) wr[i] = wrow[lane + i * 64];
    float4 a = reinterpret_cast<const float4*>(x)[tid * 2];
    float4 b = reinterpret_cast<const float4*>(x)[tid * 2 + 1];
    float ss = blockSum256(dot4(a, a) + dot4(b, b), red);
    float scale = rsqrtf(ss / (float)DIMN + 1e-6f);
    float4 wa = reinterpret_cast<const float4*>(anw)[tid * 2];
    float4 wb = reinterpret_cast<const float4*>(anw)[tid * 2 + 1];
    reinterpret_cast<float4*>(xn)[tid * 2] =
        make_float4(a.x * scale * wa.x, a.y * scale * wa.y, a.z * scale * wa.z, a.w * scale * wa.w);
    reinterpret_cast<float4*>(xn)[tid * 2 + 1] =
        make_float4(b.x * scale * wb.x, b.y * scale * wb.y, b.z * scale * wb.z, b.w * scale * wb.w);
    if (blockIdx.x == 0) {
        float4 z = make_float4(0.f, 0.f, 0.f, 0.f);
        reinterpret_cast<float4*>(ws + WS_ATTN)[tid * 2] = z;
        reinterpret_cast<float4*>(ws + WS_ATTN)[tid * 2 + 1] = z;
    }
    __syncthreads();
    const float4* xv = reinterpret_cast<const float4*>(xn);
    float acc = 0.f;
#pragma unroll
    for (int i = 0; i < 8; ++i) acc += dot4(wr[i], xv[lane + i * 64]);
    acc = waveSum(acc);
    if (lane == 0) {
        float y = acc + B[r];
        if (mat == 0) ws[WS_Q + r] = y;
        else {
            float* dst = (mat == 1) ? cacheK : cacheV;
            dst[(size_t)posp[0] * DIMN + r] = y;
        }
    }
}

__global__ __launch_bounds__(256) void k_scores(
        const float* __restrict__ cacheK, float* __restrict__ ws,
        const int* __restrict__ posp) {
    int wave = threadIdx.x >> 6, lane = threadIdx.x & 63;
    int t = blockIdx.x * 4 + wave;
    int L = posp[0] + 1;
    if (t >= L) return;
    const float4* krow = reinterpret_cast<const float4*>(cacheK + (size_t)t * DIMN);
    const float4* qv = reinterpret_cast<const float4*>(ws + WS_Q);
    float acc = 0.f;
#pragma unroll
    for (int i = 0; i < 8; ++i) {
        int ch = lane + i * 64;
        acc += dot4(krow[ch], qv[ch]);
    }
    acc = waveSum(acc);
    if (lane == 0) ws[WS_SC + t] = acc * 0.022097086912079608f;
}

__global__ __launch_bounds__(256) void k_av(
        const float* __restrict__ cacheV, float* __restrict__ ws,
        const int* __restrict__ posp) {
    __shared__ float red[4];
    int tid = threadIdx.x;
    int L = posp[0] + 1;
    float m = -1e30f;
    for (int i = tid; i < L; i += 256) m = fmaxf(m, ws[WS_SC + i]);
    m = blockMax256(m, red);
    float s = 0.f;
    for (int i = tid; i < L; i += 256) s += expf(ws[WS_SC + i] - m);
    s = blockSum256(s, red);
    float inv = 1.0f / s;
    int T = gridDim.y, chunk = blockIdx.y;
    int t0 = (int)((long long)chunk * L / T);
    int t1 = (int)((long long)(chunk + 1) * L / T);
    int c2 = blockIdx.x * 256 + tid;
    const float2* Vp = reinterpret_cast<const float2*>(cacheV);
    float a0 = 0.f, a1 = 0.f;
    for (int t = t0; t < t1; ++t) {
        float p = expf(ws[WS_SC + t] - m) * inv;
        float2 v = Vp[(size_t)t * (DIMN / 2) + c2];
        a0 += p * v.x;
        a1 += p * v.y;
    }
    atomicAdd(&ws[WS_ATTN + 2 * c2], a0);
    atomicAdd(&ws[WS_ATTN + 2 * c2 + 1], a1);
}

__global__ __launch_bounds__(256) void k_oproj(
        const float* __restrict__ x, const float* __restrict__ ow,
        const float* __restrict__ ob, float* __restrict__ ws) {
    int wave = threadIdx.x >> 6, lane = threadIdx.x & 63;
    int r = blockIdx.x * 4 + wave;
    const float4* wrow = reinterpret_cast<const float4*>(ow + (size_t)r * DIMN);
    const float4* av = reinterpret_cast<const float4*>(ws + WS_ATTN);
    float acc = 0.f;
#pragma unroll
    for (int i = 0; i < 8; ++i) {
        int ch = lane + i * 64;
        acc += dot4(wrow[ch], av[ch]);
    }
    acc = waveSum(acc);
    if (lane == 0) ws[WS_X1 + r] = x[r] + acc + ob[r];
}

__global__ __launch_bounds__(256) void k_fc1(
        const float* __restrict__ w1, const float* __restrict__ b1,
        const float* __restrict__ mnw, float* __restrict__ ws) {
    __shared__ float hn[DIMN];
    __shared__ float red[4];
    int tid = threadIdx.x, wave = tid >> 6, lane = tid & 63;
    int r = blockIdx.x * 4 + wave;
    const float4* wrow = reinterpret_cast<const float4*>(w1 + (size_t)r * DIMN);
    float4 wr[8];
#pragma unroll
    for (int i = 0; i < 8; ++i) wr[i] = wrow[lane + i * 64];
    float4 a = reinterpret_cast<const float4*>(ws + WS_X1)[tid * 2];
    float4 b = reinterpret_cast<const float4*>(ws + WS_X1)[tid * 2 + 1];
    float ss = blockSum256(dot4(a, a) + dot4(b, b), red);
    float scale = rsqrtf(ss / (float)DIMN + 1e-6f);
    float4 wa = reinterpret_cast<const float4*>(mnw)[tid * 2];
    float4 wb = reinterpret_cast<const float4*>(mnw)[tid * 2 + 1];
    reinterpret_cast<float4*>(hn)[tid * 2] =
        make_float4(a.x * scale * wa.x, a.y * scale * wa.y, a.z * scale * wa.z, a.w * scale * wa.w);
    reinterpret_cast<float4*>(hn)[tid * 2 + 1] =
        make_float4(b.x * scale * wb.x, b.y * scale * wb.y, b.z * scale * wb.z, b.w * scale * wb.w);
    __syncthreads();
    const float4* hv = reinterpret_cast<const float4*>(hn);
    float acc = 0.f;
#pragma unroll
    for (int i = 0; i < 8; ++i) acc += dot4(wr[i], hv[lane + i * 64]);
    acc = waveSum(acc);
    if (lane == 0) {
        float t = acc + b1[r];
        ws[WS_H + r] = 0.5f * t * (1.0f + erff(t * 0.70710678118654752f));
    }
}

__global__ __launch_bounds__(256) void k_fc2(
        const float* __restrict__ w2, const float* __restrict__ b2,
        const float* __restrict__ ws, float* __restrict__ out) {
    int wave = threadIdx.x >> 6, lane = threadIdx.x & 63;
    int r = blockIdx.x * 4 + wave;
    const float4* wrow = reinterpret_cast<const float4*>(w2 + (size_t)r * HDIM);
    const float4* hv = reinterpret_cast<const float4*>(ws + WS_H);
    float acc = 0.f;
#pragma unroll
    for (int i = 0; i < 32; ++i) {
        int ch = lane + i * 64;
        acc += dot4(wrow[ch], hv[ch]);
    }
    acc = waveSum(acc);
    if (lane == 0) out[r] = ws[WS_X1 + r] + acc + b2[r];
}

extern "C" void kernel_launch(void* const* d_in, const int* in_sizes, int n_in,
                              void* d_out, int out_size, void* d_ws, size_t ws_size,
                              hipStream_t stream) {
    const float* x   = (const float*)d_in[0];
    float* cacheK    = (float*)d_in[1];
    float* cacheV    = (float*)d_in[2];
    const float* anw = (const float*)d_in[3];
    const float* qw  = (const float*)d_in[4];
    const float* qb  = (const float*)d_in[5];
    const float* kw  = (const float*)d_in[6];
    const float* kb  = (const float*)d_in[7];
    const float* vw  = (const float*)d_in[8];
    const float* vb  = (const float*)d_in[9];
    const float* ow  = (const float*)d_in[10];
    const float* ob  = (const float*)d_in[11];
    const float* mnw = (const float*)d_in[12];
    const float* w1  = (const float*)d_in[13];
    const float* b1  = (const float*)d_in[14];
    const float* w2  = (const float*)d_in[15];
    const float* b2  = (const float*)d_in[16];
    const int* posp  = (const int*)d_in[17];
    float* ws = (float*)d_ws;
    float* out = (float*)d_out;

    void* args[] = {&x, &cacheK, &cacheV, &anw, &qw, &qb, &kw, &kb, &vw, &vb,
                    &ow, &ob, &mnw, &w1, &b1, &w2, &b2, &posp, &ws, &out};
    hipError_t e = hipLaunchCooperativeKernel((void*)k_fused, dim3(512), dim3(256),
                                              args, 0, stream);
    if (e != hipSuccess) {
        (void)hipGetLastError();  // clear sticky error, fall back to 6-kernel path
        k_qkv<<<1536, 256, 0, stream>>>(x, anw, ws, qw, qb, kw, kb, vw, vb, cacheK, cacheV, posp);
        k_scores<<<1025, 256, 0, stream>>>(cacheK, ws, posp);
        k_av<<<dim3(4, 128), 256, 0, stream>>>(cacheV, ws, posp);
        k_oproj<<<512, 256, 0, stream>>>(x, ow, ob, ws);
        k_fc1<<<2048, 256, 0, stream>>>(w1, b1, mnw, ws);
        k_fc2<<<512, 256, 0, stream>>>(w2, b2, ws, out);
    }
}